// Round 2
// baseline (655.068 us; speedup 1.0000x reference)
//
#include <hip/hip_runtime.h>

// CRF NLL forward (log-partition) + gold score, fused.
// One wave per batch element, lane t owns tag t.
// Exp-space recursion E_{s+1} = exp(feats_s) * (W @ E_s), W = exp(transitions),
// exact power-of-2 renormalization each step (integer log2 offset C).
// Matvec broadcast via v_readlane -> SGPR, fmaf with SGPR operand.
// masks[b,s] == (s < lengths[b]) by construction, so lengths suffice.
//
// R2 fix: __launch_bounds__(256, 1) — R1's default occupancy target capped
// VGPRs at 52, spilling the 64-entry W row to scratch (L2-backed), costing
// ~900 cyc/step. min-1-wave/EU lifts the cap to ~512 VGPRs.

#define TT 64

__device__ __forceinline__ float readlane_f(float v, int lane) {
  return __builtin_bit_cast(float, __builtin_amdgcn_readlane(__builtin_bit_cast(int, v), lane));
}

__global__ __launch_bounds__(256, 1) void crf_fwd_kernel(
    const float* __restrict__ feats, const int* __restrict__ tags,
    const int* __restrict__ lengths, const float* __restrict__ trans,
    const int* __restrict__ p_start, const int* __restrict__ p_stop,
    float* __restrict__ out, int B, int S) {
  const int wave = threadIdx.x >> 6;
  const int lane = threadIdx.x & 63;
  const int b = blockIdx.x * 4 + wave;

  // raw transitions in LDS for the gold-score gather (uniform-address reads)
  __shared__ float s_trans[TT * TT];
  if (wave == 0) {
    for (int i = lane * 4; i < TT * TT; i += 64 * 4) {
      *reinterpret_cast<float4*>(&s_trans[i]) =
          *reinterpret_cast<const float4*>(trans + i);
    }
  }
  __syncthreads();

  if (b >= B) return;

  const int start = *p_start;
  const int stop = *p_stop;
  const int len = lengths[b];

  // lane t holds W[t][p] = exp(trans[t][p]) for all p (64 VGPRs)
  float w[TT];
#pragma unroll
  for (int p = 0; p < TT; p += 4) {
    float4 r = *reinterpret_cast<const float4*>(trans + lane * TT + p);
    w[p + 0] = __expf(r.x);
    w[p + 1] = __expf(r.y);
    w[p + 2] = __expf(r.z);
    w[p + 3] = __expf(r.w);
  }
  // stop-transition weights for the final logsumexp
  float ws = __expf(trans[stop * TT + lane]);

  const float* fb = feats + (size_t)b * S * TT + lane;
  const int* tb = tags + (size_t)b * S;

  // exp-space state: E[t] = exp(fv[t] - C*ln2); init fv = -1e4 except start=0
  float E = (lane == start) ? 1.0f : 0.0f;
  int C = 0;          // log2 renorm offset (exact integer)
  float gold = 0.0f;  // replicated uniform across lanes
  int tprev = start;

  // software pipeline: feats + tags 3 steps ahead
  int i1 = 1 < S ? 1 : S - 1;
  int i2 = 2 < S ? 2 : S - 1;
  float f0 = fb[0];
  float f1 = fb[(size_t)TT * i1];
  float f2 = fb[(size_t)TT * i2];
  int tg0 = tb[0];
  int tg1 = tb[i1];
  int tg2 = tb[i2];

#pragma unroll 1
  for (int s = 0; s < len; ++s) {
    // matvec: acc[t] = sum_p W[t][p] * E[p]
    float a0 = 0.f, a1 = 0.f, a2 = 0.f, a3 = 0.f;
#pragma unroll
    for (int p = 0; p < TT; p += 4) {
      a0 = fmaf(w[p + 0], readlane_f(E, p + 0), a0);
      a1 = fmaf(w[p + 1], readlane_f(E, p + 1), a1);
      a2 = fmaf(w[p + 2], readlane_f(E, p + 2), a2);
      a3 = fmaf(w[p + 3], readlane_f(E, p + 3), a3);
    }
    float acc = (a0 + a1) + (a2 + a3);
    float fexp = __expf(f0);
    float Eraw = fexp * acc;

    // exact power-of-2 renorm by exponent of lane 3 (always finite > 0)
    unsigned rb = (unsigned)__builtin_amdgcn_readlane(__builtin_bit_cast(int, Eraw), 3);
    int k = (int)((rb >> 23) & 0xFFu) - 127;
    C += k;
    float scale = __builtin_bit_cast(float, (unsigned)(127 - k) << 23);
    E = Eraw * scale;

    // gold path: trans[tag_s, tag_{s-1}] + feats[b,s,tag_s]
    int tgu = __builtin_amdgcn_readfirstlane(tg0);
    float tr = s_trans[tgu * TT + tprev];
    gold += tr + readlane_f(f0, tgu);
    tprev = tgu;

    // rotate pipelines
    f0 = f1;
    f1 = f2;
    tg0 = tg1;
    tg1 = tg2;
    int nidx = s + 3;
    nidx = nidx < S ? nidx : S - 1;
    f2 = fb[(size_t)TT * nidx];
    tg2 = tb[nidx];
  }

  // ends = tags[b, len-1] (= tprev); add trans[stop, ends]
  gold += s_trans[stop * TT + tprev];

  // alpha = C*ln2 + log(sum_t E[t] * exp(trans[stop, t]))
  float v = E * ws;
#pragma unroll
  for (int off = 32; off >= 1; off >>= 1) v += __shfl_xor(v, off, 64);
  float alpha = __logf(v) + (float)C * 0.6931471805599453f;

  if (lane == 0) out[b] = alpha - gold;
}

extern "C" void kernel_launch(void* const* d_in, const int* in_sizes, int n_in,
                              void* d_out, int out_size, void* d_ws, size_t ws_size,
                              hipStream_t stream) {
  const float* feats = (const float*)d_in[0];
  const int* tags = (const int*)d_in[1];
  const int* lengths = (const int*)d_in[2];
  // d_in[3] = masks: unused; masks[b,s] == (s < lengths[b]) by construction
  const float* trans = (const float*)d_in[4];
  const int* p_start = (const int*)d_in[5];
  const int* p_stop = (const int*)d_in[6];
  float* out = (float*)d_out;

  int B = in_sizes[2];
  int S = in_sizes[1] / B;
  int blocks = (B + 3) / 4;
  crf_fwd_kernel<<<blocks, 256, 0, stream>>>(feats, tags, lengths, trans,
                                             p_start, p_stop, out, B, S);
}

// Round 3
// 617.641 us; speedup vs baseline: 1.0606x; 1.0606x over previous
//
#include <hip/hip_runtime.h>

// CRF NLL forward (log-partition) + gold score, fused.
// One wave per batch element, lane t owns tag t.
// Exp-space recursion E_{s+1} = exp(feats_s) * (W @ E_s), W = exp(transitions),
// exact power-of-2 renormalization each step (integer log2 offset C).
// Matvec broadcast via v_readlane -> SGPR, fmaf with SGPR operand.
// masks[b,s] == (s < lengths[b]) by construction, so lengths suffice.
//
// R3 fix: R1/R2 kept W in a private ARRAY (float w[64]) — AMDGPU PromoteAlloca
// refuses arrays this large, so W lived in scratch (VGPR_Count=52 both rounds,
// ~900 cyc/step of L2-backed reloads). Replace with 64 NAMED scalars
// (macro-generated) which mem2reg promotes unconditionally.
// Also: 64-thread blocks (1 wave = 1 batch, 512 blocks) to spread waves over
// all 256 CUs instead of packing 4 waves into 128 CUs.

#define TT 64

__device__ __forceinline__ float readlane_f(float v, int lane) {
  return __builtin_bit_cast(float, __builtin_amdgcn_readlane(__builtin_bit_cast(int, v), lane));
}

#define DECLW(a,b_,c,d_) float w##a, w##b_, w##c, w##d_;
#define LOADW(a,b_,c,d_,off)                                              \
  {                                                                       \
    float4 r = *reinterpret_cast<const float4*>(trans + lane * TT + off); \
    w##a = __expf(r.x);                                                   \
    w##b_ = __expf(r.y);                                                  \
    w##c = __expf(r.z);                                                   \
    w##d_ = __expf(r.w);                                                  \
  }
#define FMAG(a,b_,c,d_)                    \
  a0 = fmaf(w##a, readlane_f(E, a), a0);   \
  a1 = fmaf(w##b_, readlane_f(E, b_), a1); \
  a2 = fmaf(w##c, readlane_f(E, c), a2);   \
  a3 = fmaf(w##d_, readlane_f(E, d_), a3);

__global__ __launch_bounds__(64, 1) void crf_fwd_kernel(
    const float* __restrict__ feats, const int* __restrict__ tags,
    const int* __restrict__ lengths, const float* __restrict__ trans,
    const int* __restrict__ p_start, const int* __restrict__ p_stop,
    float* __restrict__ out, int B, int S) {
  const int lane = threadIdx.x;  // block = exactly one wave
  const int b = blockIdx.x;
  if (b >= B) return;

  // raw transitions in LDS for the gold-score gather (uniform-address reads)
  __shared__ float s_trans[TT * TT];
  for (int i = lane * 4; i < TT * TT; i += 64 * 4) {
    *reinterpret_cast<float4*>(&s_trans[i]) =
        *reinterpret_cast<const float4*>(trans + i);
  }
  __syncthreads();

  const int start = *p_start;
  const int stop = *p_stop;
  const int len = lengths[b];

  // lane t holds W[t][p] = exp(trans[t][p]) in 64 named registers
  DECLW(0, 1, 2, 3) DECLW(4, 5, 6, 7) DECLW(8, 9, 10, 11) DECLW(12, 13, 14, 15)
  DECLW(16, 17, 18, 19) DECLW(20, 21, 22, 23) DECLW(24, 25, 26, 27) DECLW(28, 29, 30, 31)
  DECLW(32, 33, 34, 35) DECLW(36, 37, 38, 39) DECLW(40, 41, 42, 43) DECLW(44, 45, 46, 47)
  DECLW(48, 49, 50, 51) DECLW(52, 53, 54, 55) DECLW(56, 57, 58, 59) DECLW(60, 61, 62, 63)

  LOADW(0, 1, 2, 3, 0) LOADW(4, 5, 6, 7, 4)
  LOADW(8, 9, 10, 11, 8) LOADW(12, 13, 14, 15, 12)
  LOADW(16, 17, 18, 19, 16) LOADW(20, 21, 22, 23, 20)
  LOADW(24, 25, 26, 27, 24) LOADW(28, 29, 30, 31, 28)
  LOADW(32, 33, 34, 35, 32) LOADW(36, 37, 38, 39, 36)
  LOADW(40, 41, 42, 43, 40) LOADW(44, 45, 46, 47, 44)
  LOADW(48, 49, 50, 51, 48) LOADW(52, 53, 54, 55, 52)
  LOADW(56, 57, 58, 59, 56) LOADW(60, 61, 62, 63, 60)

  // stop-transition weights for the final logsumexp
  float ws = __expf(trans[stop * TT + lane]);

  const float* fb = feats + (size_t)b * S * TT + lane;
  const int* tb = tags + (size_t)b * S;

  // exp-space state: E[t] = exp(fv[t] - C*ln2); init fv = -1e4 except start=0
  float E = (lane == start) ? 1.0f : 0.0f;
  int C = 0;          // log2 renorm offset (exact integer)
  float gold = 0.0f;  // replicated uniform across lanes
  int tprev = start;

  // software pipeline: feats + tags 3 steps ahead
  int i1 = 1 < S ? 1 : S - 1;
  int i2 = 2 < S ? 2 : S - 1;
  float f0 = fb[0];
  float f1 = fb[(size_t)TT * i1];
  float f2 = fb[(size_t)TT * i2];
  int tg0 = tb[0];
  int tg1 = tb[i1];
  int tg2 = tb[i2];

#pragma unroll 1
  for (int s = 0; s < len; ++s) {
    // matvec: acc[t] = sum_p W[t][p] * E[p], broadcast via readlane
    float a0 = 0.f, a1 = 0.f, a2 = 0.f, a3 = 0.f;
    FMAG(0, 1, 2, 3) FMAG(4, 5, 6, 7)
    FMAG(8, 9, 10, 11) FMAG(12, 13, 14, 15)
    FMAG(16, 17, 18, 19) FMAG(20, 21, 22, 23)
    FMAG(24, 25, 26, 27) FMAG(28, 29, 30, 31)
    FMAG(32, 33, 34, 35) FMAG(36, 37, 38, 39)
    FMAG(40, 41, 42, 43) FMAG(44, 45, 46, 47)
    FMAG(48, 49, 50, 51) FMAG(52, 53, 54, 55)
    FMAG(56, 57, 58, 59) FMAG(60, 61, 62, 63)
    float acc = (a0 + a1) + (a2 + a3);
    float fexp = __expf(f0);
    float Eraw = fexp * acc;

    // exact power-of-2 renorm by exponent of lane 3 (always finite > 0)
    unsigned rb = (unsigned)__builtin_amdgcn_readlane(__builtin_bit_cast(int, Eraw), 3);
    int k = (int)((rb >> 23) & 0xFFu) - 127;
    C += k;
    float scale = __builtin_bit_cast(float, (unsigned)(127 - k) << 23);
    E = Eraw * scale;

    // gold path: trans[tag_s, tag_{s-1}] + feats[b,s,tag_s]
    int tgu = __builtin_amdgcn_readfirstlane(tg0);
    float tr = s_trans[tgu * TT + tprev];
    gold += tr + readlane_f(f0, tgu);
    tprev = tgu;

    // rotate pipelines
    f0 = f1;
    f1 = f2;
    tg0 = tg1;
    tg1 = tg2;
    int nidx = s + 3;
    nidx = nidx < S ? nidx : S - 1;
    f2 = fb[(size_t)TT * nidx];
    tg2 = tb[nidx];
  }

  // ends = tags[b, len-1] (= tprev); add trans[stop, ends]
  gold += s_trans[stop * TT + tprev];

  // alpha = C*ln2 + log(sum_t E[t] * exp(trans[stop, t]))
  float v = E * ws;
#pragma unroll
  for (int off = 32; off >= 1; off >>= 1) v += __shfl_xor(v, off, 64);
  float alpha = __logf(v) + (float)C * 0.6931471805599453f;

  if (lane == 0) out[b] = alpha - gold;
}

extern "C" void kernel_launch(void* const* d_in, const int* in_sizes, int n_in,
                              void* d_out, int out_size, void* d_ws, size_t ws_size,
                              hipStream_t stream) {
  const float* feats = (const float*)d_in[0];
  const int* tags = (const int*)d_in[1];
  const int* lengths = (const int*)d_in[2];
  // d_in[3] = masks: unused; masks[b,s] == (s < lengths[b]) by construction
  const float* trans = (const float*)d_in[4];
  const int* p_start = (const int*)d_in[5];
  const int* p_stop = (const int*)d_in[6];
  float* out = (float*)d_out;

  int B = in_sizes[2];
  int S = in_sizes[1] / B;
  crf_fwd_kernel<<<B, 64, 0, stream>>>(feats, tags, lengths, trans,
                                       p_start, p_stop, out, B, S);
}

// Round 4
// 417.950 us; speedup vs baseline: 1.5673x; 1.4778x over previous
//
#include <hip/hip_runtime.h>

// CRF NLL forward (log-partition) + gold score.
// One wave per batch element, lane t owns tag t.
// Exp-space recursion E_{s+1} = exp(feats_s) * (W @ E_s), W = exp(transitions),
// exact power-of-2 renormalization every 4 steps (integer log2 offset C).
// Matvec broadcast via v_readlane -> SGPR, fmaf with SGPR operand.
//
// R4: serial loop stripped to matvec only.
//  - gold score (tags/trans/emit gathers) moved OUT of the loop: lane-parallel
//    strided pass + wave reduction (it never depended on E).
//  - feats prefetch deepened to 16 rows via 8-unrolled body with named ring:
//    f0..f7 raw loads in flight, e0..e7 = expf(f) computed one group ahead,
//    so expf is off the E critical chain.
//  - renorm every 4 steps (growth <=~2^60/4steps + ~2^20 spread < 2^127).

#define TT 64

__device__ __forceinline__ float readlane_f(float v, int lane) {
  return __builtin_bit_cast(float, __builtin_amdgcn_readlane(__builtin_bit_cast(int, v), lane));
}

#define DECLW(a,b_,c,d_) float w##a, w##b_, w##c, w##d_;
#define LOADW(a,b_,c,d_,off)                                              \
  {                                                                       \
    float4 r = *reinterpret_cast<const float4*>(trans + lane * TT + off); \
    w##a = __expf(r.x);                                                   \
    w##b_ = __expf(r.y);                                                  \
    w##c = __expf(r.z);                                                   \
    w##d_ = __expf(r.w);                                                  \
  }
#define FMAG(a,b_,c,d_)                    \
  a0 = fmaf(w##a, readlane_f(E, a), a0);   \
  a1 = fmaf(w##b_, readlane_f(E, b_), a1); \
  a2 = fmaf(w##c, readlane_f(E, c), a2);   \
  a3 = fmaf(w##d_, readlane_f(E, d_), a3);

#define MATVEC(accname)                                        \
  float a0 = 0.f, a1 = 0.f, a2 = 0.f, a3 = 0.f;                \
  FMAG(0, 1, 2, 3) FMAG(4, 5, 6, 7)                            \
  FMAG(8, 9, 10, 11) FMAG(12, 13, 14, 15)                      \
  FMAG(16, 17, 18, 19) FMAG(20, 21, 22, 23)                    \
  FMAG(24, 25, 26, 27) FMAG(28, 29, 30, 31)                    \
  FMAG(32, 33, 34, 35) FMAG(36, 37, 38, 39)                    \
  FMAG(40, 41, 42, 43) FMAG(44, 45, 46, 47)                    \
  FMAG(48, 49, 50, 51) FMAG(52, 53, 54, 55)                    \
  FMAG(56, 57, 58, 59) FMAG(60, 61, 62, 63)                    \
  float accname = (a0 + a1) + (a2 + a3);

#define RENORM()                                                                      \
  {                                                                                   \
    unsigned rb = (unsigned)__builtin_amdgcn_readlane(__builtin_bit_cast(int, E), 3); \
    int k = (int)((rb >> 23) & 0xFFu) - 127;                                          \
    C += k;                                                                           \
    E *= __builtin_bit_cast(float, (unsigned)(127 - k) << 23);                        \
  }

// step: consume e##J (exp of row s+J, ready since last group), advance E,
// refill e##J from f##J (row s+J+8, load issued last group), issue load of
// row s+J+16 into f##J.
#define STEP(J, SBASE)                     \
  {                                        \
    float ecur = e##J;                     \
    MATVEC(acc);                           \
    E = ecur * acc;                        \
    e##J = __expf(f##J);                   \
    int pidx = (SBASE) + (J) + 16;         \
    pidx = pidx < S ? pidx : S - 1;        \
    f##J = fb[(size_t)TT * pidx];          \
  }

__global__ __launch_bounds__(64, 1) void crf_fwd_kernel(
    const float* __restrict__ feats, const int* __restrict__ tags,
    const int* __restrict__ lengths, const float* __restrict__ trans,
    const int* __restrict__ p_start, const int* __restrict__ p_stop,
    float* __restrict__ out, int B, int S) {
  const int lane = threadIdx.x;  // block = exactly one wave
  const int b = blockIdx.x;
  if (b >= B) return;

  // raw transitions in LDS for the gold-score gathers
  __shared__ float s_trans[TT * TT];
  for (int i = lane * 4; i < TT * TT; i += 64 * 4) {
    *reinterpret_cast<float4*>(&s_trans[i]) =
        *reinterpret_cast<const float4*>(trans + i);
  }
  __syncthreads();

  const int start = *p_start;
  const int stop = *p_stop;
  const int len = lengths[b];

  // lane t holds W[t][p] = exp(trans[t][p]) in 64 named registers
  DECLW(0, 1, 2, 3) DECLW(4, 5, 6, 7) DECLW(8, 9, 10, 11) DECLW(12, 13, 14, 15)
  DECLW(16, 17, 18, 19) DECLW(20, 21, 22, 23) DECLW(24, 25, 26, 27) DECLW(28, 29, 30, 31)
  DECLW(32, 33, 34, 35) DECLW(36, 37, 38, 39) DECLW(40, 41, 42, 43) DECLW(44, 45, 46, 47)
  DECLW(48, 49, 50, 51) DECLW(52, 53, 54, 55) DECLW(56, 57, 58, 59) DECLW(60, 61, 62, 63)

  LOADW(0, 1, 2, 3, 0) LOADW(4, 5, 6, 7, 4)
  LOADW(8, 9, 10, 11, 8) LOADW(12, 13, 14, 15, 12)
  LOADW(16, 17, 18, 19, 16) LOADW(20, 21, 22, 23, 20)
  LOADW(24, 25, 26, 27, 24) LOADW(28, 29, 30, 31, 28)
  LOADW(32, 33, 34, 35, 32) LOADW(36, 37, 38, 39, 36)
  LOADW(40, 41, 42, 43, 40) LOADW(44, 45, 46, 47, 44)
  LOADW(48, 49, 50, 51, 48) LOADW(52, 53, 54, 55, 52)
  LOADW(56, 57, 58, 59, 56) LOADW(60, 61, 62, 63, 60)

  float ws = __expf(trans[stop * TT + lane]);

  const float* fbase = feats + (size_t)b * S * TT;
  const float* fb = fbase + lane;
  const int* tb = tags + (size_t)b * S;

  // exp-space state
  float E = (lane == start) ? 1.0f : 0.0f;
  int C = 0;

  // prime the pipeline: e_j = expf(row j); f_j = row j+8 in flight
#define PRIME(J)                                            \
  float e##J = __expf(fb[(size_t)TT * ((J) < S ? (J) : S - 1)]); \
  float f##J = fb[(size_t)TT * (((J) + 8) < S ? ((J) + 8) : S - 1)];
  PRIME(0) PRIME(1) PRIME(2) PRIME(3)
  PRIME(4) PRIME(5) PRIME(6) PRIME(7)
#undef PRIME

  int s = 0;
#pragma unroll 1
  for (; s + 8 <= len; s += 8) {
    STEP(0, s) STEP(1, s) STEP(2, s) STEP(3, s) RENORM();
    STEP(4, s) STEP(5, s) STEP(6, s) STEP(7, s) RENORM();
  }
#pragma unroll 1
  for (; s < len; ++s) {  // tail <8 iters: rows are L1-hot (prefetched)
    float ecur = __expf(fb[(size_t)TT * s]);
    MATVEC(acc);
    E = ecur * acc;
    RENORM();
  }

  // alpha = C*ln2 + log(sum_t E[t] * exp(trans[stop, t]))
  float v = E * ws;
#pragma unroll
  for (int off = 32; off >= 1; off >>= 1) v += __shfl_xor(v, off, 64);
  float alpha = __logf(v) + (float)C * 0.6931471805599453f;

  // gold path score, lane-parallel over steps (independent of E recursion):
  // lane j handles steps j, j+64, ... : trans[tag_s, tag_{s-1}] + feats[b,s,tag_s]
  float gs = 0.0f;
#pragma unroll 1
  for (int s0 = 0; s0 < len; s0 += 64) {
    int si = s0 + lane;
    if (si < len) {
      int t = tb[si];
      int tp = (si == 0) ? start : tb[si - 1];
      gs += s_trans[t * TT + tp] + fbase[(size_t)si * TT + t];
    }
  }
#pragma unroll
  for (int off = 32; off >= 1; off >>= 1) gs += __shfl_xor(gs, off, 64);
  int tend = tb[len - 1];
  float gold = gs + s_trans[stop * TT + tend];

  if (lane == 0) out[b] = alpha - gold;
}

extern "C" void kernel_launch(void* const* d_in, const int* in_sizes, int n_in,
                              void* d_out, int out_size, void* d_ws, size_t ws_size,
                              hipStream_t stream) {
  const float* feats = (const float*)d_in[0];
  const int* tags = (const int*)d_in[1];
  const int* lengths = (const int*)d_in[2];
  // d_in[3] = masks: unused; masks[b,s] == (s < lengths[b]) by construction
  const float* trans = (const float*)d_in[4];
  const int* p_start = (const int*)d_in[5];
  const int* p_stop = (const int*)d_in[6];
  float* out = (float*)d_out;

  int B = in_sizes[2];
  int S = in_sizes[1] / B;
  crf_fwd_kernel<<<B, 64, 0, stream>>>(feats, tags, lengths, trans,
                                       p_start, p_stop, out, B, S);
}